// Round 5
// baseline (644.200 us; speedup 1.0000x reference)
//
#include <hip/hip_runtime.h>

#define N_NODES 100000
#define F_IN 128
#define HID 256
#define NCLS 64
#define N_EDGES 1600000

typedef _Float16 f16;
typedef f16 half8 __attribute__((ext_vector_type(8)));
typedef f16 half4 __attribute__((ext_vector_type(4)));
typedef float f32x4 __attribute__((ext_vector_type(4)));

// ---------------------------------------------------------------------------
// CSR build: count -> scan -> scatter(raw w) -> segment deg -> renorm
// ---------------------------------------------------------------------------
__global__ void k_zero(int* __restrict__ cnt, int n) {
    int i = blockIdx.x * 256 + threadIdx.x;
    if (i < n) cnt[i] = 0;
}

__global__ void k_cnt(const int* __restrict__ dst, int* __restrict__ cnt, int e) {
    int i = blockIdx.x * 256 + threadIdx.x;
    if (i < e) atomicAdd(&cnt[dst[i]], 1);
}

__global__ void k_scan1(const int* __restrict__ cnt, int* __restrict__ incl,
                        int* __restrict__ bsum, int n) {
    __shared__ int s[256];
    int t = threadIdx.x;
    int i = blockIdx.x * 256 + t;
    int v = (i < n) ? cnt[i] : 0;
    s[t] = v;
    __syncthreads();
    #pragma unroll
    for (int off = 1; off < 256; off <<= 1) {
        int x = (t >= off) ? s[t - off] : 0;
        __syncthreads();
        s[t] += x;
        __syncthreads();
    }
    if (i < n) incl[i] = s[t];
    if (t == 255) bsum[blockIdx.x] = s[255];
}

__global__ void k_scan2(const int* __restrict__ bsum, int* __restrict__ boff, int nb) {
    __shared__ int s[512];
    int t = threadIdx.x;
    int v = (t < nb) ? bsum[t] : 0;
    s[t] = v;
    __syncthreads();
    #pragma unroll
    for (int off = 1; off < 512; off <<= 1) {
        int x = (t >= off) ? s[t - off] : 0;
        __syncthreads();
        s[t] += x;
        __syncthreads();
    }
    if (t < nb) boff[t] = s[t] - v;
}

__global__ void k_scan3(int* __restrict__ row, const int* __restrict__ cnt,
                        const int* __restrict__ boff, int n) {
    int i = blockIdx.x * 256 + threadIdx.x;
    if (i < n) row[i] = row[i] - cnt[i] + boff[i >> 8];
}

// scatter edges into CSR with RAW weight; row[] acts as cursor -> row_end
__global__ void k_scatter(const int* __restrict__ src, const int* __restrict__ dst,
                          const float* __restrict__ w,
                          int* __restrict__ row, int2* __restrict__ csr, int e) {
    int i = blockIdx.x * 256 + threadIdx.x;
    if (i < e) {
        int d = dst[i];
        int pos = atomicAdd(&row[d], 1);
        csr[pos] = make_int2(src[i], __float_as_int(w[i]));
    }
}

// per-node: deg = 1 + sum(raw w in segment); dis = deg^-1/2; selfnorm = 1/deg
__global__ void k_segdeg(const int2* __restrict__ csr, const int* __restrict__ row,
                         const int* __restrict__ cnt, float* __restrict__ dis,
                         float* __restrict__ selfnorm, int n) {
    int i = blockIdx.x * 256 + threadIdx.x;
    if (i >= n) return;
    int end = row[i];
    int st = end - cnt[i];
    float s = 1.0f;   // self-loop
    for (int e = st; e < end; ++e) s += __int_as_float(csr[e].y);
    float d = rsqrtf(s);
    dis[i] = d;
    selfnorm[i] = d * d;
}

// per-edge (4 lanes per node): w_norm = dis[src] * w * dis[dst]
__global__ void k_renorm(int2* __restrict__ csr, const int* __restrict__ row,
                         const int* __restrict__ cnt, const float* __restrict__ dis,
                         int n) {
    int g = blockIdx.x * 256 + threadIdx.x;
    int node = g >> 2;
    if (node >= n) return;
    int lane = g & 3;
    int end = row[node];
    int st = end - cnt[node];
    float dd = dis[node];
    for (int e = st + lane; e < end; e += 4) {
        int2 v = csr[e];
        float nw = dis[v.x] * __int_as_float(v.y) * dd;
        csr[e].y = __float_as_int(nw);
    }
}

// ---------------------------------------------------------------------------
// dtype conversion helpers
// ---------------------------------------------------------------------------
__global__ void k_f32_to_f16(const float* __restrict__ src, f16* __restrict__ dst, int n4) {
    int i = blockIdx.x * 256 + threadIdx.x;
    if (i < n4) {
        float4 v = *(const float4*)&src[(size_t)i * 4];
        half4 o;
        o[0] = (f16)v.x; o[1] = (f16)v.y; o[2] = (f16)v.z; o[3] = (f16)v.w;
        *(half4*)&dst[(size_t)i * 4] = o;
    }
}

// W[K][D] fp32 -> Wt[D][K] fp16
__global__ void k_wt(const float* __restrict__ W, f16* __restrict__ Wt, int K, int D) {
    int i = blockIdx.x * 256 + threadIdx.x;
    if (i < K * D) {
        int k = i / D, d = i % D;
        Wt[d * K + k] = (f16)W[i];
    }
}

// ---------------------------------------------------------------------------
// MFMA GEMM: out[n, c] = sum_k in[n, k] * W[k, c]  (+bias, relu if BIAS_RELU)
// BM=256 x BN=64, 4 waves, each wave 64 rows x 64 cols = 4x4 mfma 16x16x32.
// Register-prefetch pipelining: next tile's global loads issued right after
// the barrier, overlapping LDS fragment reads + MFMA.
// ---------------------------------------------------------------------------
template <int K, int DOUT, bool BIAS_RELU>
__global__ __launch_bounds__(256) void gemm_mfma(const f16* __restrict__ in,
                                                 const f16* __restrict__ Wt,  // [DOUT][K]
                                                 const float* __restrict__ bias,
                                                 f16* __restrict__ out,
                                                 int nNodes) {
    constexpr int BM = 256, BN = 64, BK = 32;
    constexpr int AP = 40;                 // padded k-stride (f16)
    constexpr int CP = 72;                 // padded col-stride for epilogue
    constexpr int SA = BM * AP;            // 10240
    constexpr int SB = BN * AP;            // 2560
    constexpr int SMEM = (SA + SB) > (BM * CP) ? (SA + SB) : (BM * CP);
    __shared__ f16 smem[SMEM];
    f16* As = smem;
    f16* Bs = smem + SA;

    const int t = threadIdx.x;
    const int w = t >> 6;
    const int lane = t & 63;
    const int quad = lane >> 4;
    const int l16 = lane & 15;
    const int nodeBase = blockIdx.x * BM;
    const int colBase = blockIdx.y * BN;

    // staging assignment: thread t covers A rows (t>>2)+p*64, k-chunk (t&3)*8
    const int ar = t >> 2;
    const int ak = (t & 3) * 8;

    half8 aReg[4];
    half8 bReg;
    #pragma unroll
    for (int p = 0; p < 4; ++p) {
        int gn = nodeBase + ar + p * 64;
        if (gn >= nNodes) gn = nNodes - 1;
        aReg[p] = *(const half8*)&in[(size_t)gn * K + ak];
    }
    bReg = *(const half8*)&Wt[(size_t)(colBase + ar) * K + ak];

    f32x4 acc[4][4] = {};

    for (int k0 = 0; k0 < K; k0 += BK) {
        #pragma unroll
        for (int p = 0; p < 4; ++p)
            *(half8*)&As[(ar + p * 64) * AP + ak] = aReg[p];
        *(half8*)&Bs[ar * AP + ak] = bReg;
        __syncthreads();

        if (k0 + BK < K) {   // prefetch next tile (overlaps compute)
            #pragma unroll
            for (int p = 0; p < 4; ++p) {
                int gn = nodeBase + ar + p * 64;
                if (gn >= nNodes) gn = nNodes - 1;
                aReg[p] = *(const half8*)&in[(size_t)gn * K + k0 + BK + ak];
            }
            bReg = *(const half8*)&Wt[(size_t)(colBase + ar) * K + k0 + BK + ak];
        }

        half8 a[4], b[4];
        #pragma unroll
        for (int rt = 0; rt < 4; ++rt)
            a[rt] = *(const half8*)&As[(w * 64 + rt * 16 + l16) * AP + quad * 8];
        #pragma unroll
        for (int ct = 0; ct < 4; ++ct)
            b[ct] = *(const half8*)&Bs[(ct * 16 + l16) * AP + quad * 8];
        #pragma unroll
        for (int rt = 0; rt < 4; ++rt)
            #pragma unroll
            for (int ct = 0; ct < 4; ++ct)
                acc[rt][ct] = __builtin_amdgcn_mfma_f32_16x16x32_f16(a[rt], b[ct], acc[rt][ct], 0, 0, 0);
        __syncthreads();
    }

    // epilogue: (+bias, relu) -> LDS (fp16) -> coalesced stores
    float bv[4];
    #pragma unroll
    for (int ct = 0; ct < 4; ++ct)
        bv[ct] = BIAS_RELU ? bias[colBase + ct * 16 + l16] : 0.0f;

    f16* Cs = smem;
    #pragma unroll
    for (int rt = 0; rt < 4; ++rt)
        #pragma unroll
        for (int ct = 0; ct < 4; ++ct)
            #pragma unroll
            for (int r = 0; r < 4; ++r) {
                int rr = w * 64 + rt * 16 + quad * 4 + r;
                float v = acc[rt][ct][r];
                if (BIAS_RELU) v = fmaxf(v + bv[ct], 0.0f);
                Cs[rr * CP + ct * 16 + l16] = (f16)v;
            }
    __syncthreads();
    #pragma unroll
    for (int p = 0; p < 8; ++p) {
        int r = (t >> 3) + p * 32;
        int gn = nodeBase + r;
        int chunk = (t & 7) * 8;
        if (gn < nNodes)
            *(half8*)&out[(size_t)gn * DOUT + colBase + chunk] =
                *(const half8*)&Cs[r * CP + chunk];
    }
}

// ---------------------------------------------------------------------------
// CSR aggregation (fp16 h): out[d,:] = sn[d]*h[d,:] (+bias) + sum_e w_e*h[src_e,:]
// TPN lanes per node, 8 cols per lane (half8 = 16B), fp32 accumulate, 4-edge unroll.
// ---------------------------------------------------------------------------
template <int DOUT, int TPN, bool HAS_BIAS, bool OUT_F32>
__global__ __launch_bounds__(256) void agg_csr(const f16* __restrict__ h,
                                               const int2* __restrict__ csr,
                                               const int* __restrict__ row,
                                               const int* __restrict__ cnt,
                                               const float* __restrict__ sn,
                                               const float* __restrict__ bias,
                                               void* __restrict__ outv, int nNodes) {
    constexpr int NPB = 256 / TPN;
    int node = blockIdx.x * NPB + threadIdx.x / TPN;
    if (node >= nNodes) return;
    int lane = threadIdx.x % TPN;
    int col = lane * 8;

    float s = sn[node];
    half8 hv = *(const half8*)&h[(size_t)node * DOUT + col];
    float acc[8];
    #pragma unroll
    for (int i = 0; i < 8; ++i)
        acc[i] = s * (float)hv[i] + (HAS_BIAS ? bias[col + i] : 0.0f);

    int end = row[node];
    int e = end - cnt[node];
    for (; e + 3 < end; e += 4) {
        int2 e0 = csr[e], e1 = csr[e + 1], e2 = csr[e + 2], e3 = csr[e + 3];
        float w0 = __int_as_float(e0.y), w1 = __int_as_float(e1.y);
        float w2 = __int_as_float(e2.y), w3 = __int_as_float(e3.y);
        half8 a0 = *(const half8*)&h[(size_t)e0.x * DOUT + col];
        half8 a1 = *(const half8*)&h[(size_t)e1.x * DOUT + col];
        half8 a2 = *(const half8*)&h[(size_t)e2.x * DOUT + col];
        half8 a3 = *(const half8*)&h[(size_t)e3.x * DOUT + col];
        #pragma unroll
        for (int i = 0; i < 8; ++i)
            acc[i] += w0 * (float)a0[i] + w1 * (float)a1[i] +
                      w2 * (float)a2[i] + w3 * (float)a3[i];
    }
    for (; e < end; ++e) {
        int2 e0 = csr[e];
        float w0 = __int_as_float(e0.y);
        half8 a0 = *(const half8*)&h[(size_t)e0.x * DOUT + col];
        #pragma unroll
        for (int i = 0; i < 8; ++i) acc[i] += w0 * (float)a0[i];
    }

    if (OUT_F32) {
        float* out = (float*)outv;
        float4 r0 = make_float4(acc[0], acc[1], acc[2], acc[3]);
        float4 r1 = make_float4(acc[4], acc[5], acc[6], acc[7]);
        *(float4*)&out[(size_t)node * DOUT + col] = r0;
        *(float4*)&out[(size_t)node * DOUT + col + 4] = r1;
    } else {
        f16* out = (f16*)outv;
        half8 o;
        #pragma unroll
        for (int i = 0; i < 8; ++i) o[i] = (f16)acc[i];
        *(half8*)&out[(size_t)node * DOUT + col] = o;
    }
}

// ---------------------------------------------------------------------------
extern "C" void kernel_launch(void* const* d_in, const int* in_sizes, int n_in,
                              void* d_out, int out_size, void* d_ws, size_t ws_size,
                              hipStream_t stream) {
    const float* x  = (const float*)d_in[0];
    const int*   ei = (const int*)d_in[1];
    const float* ew = (const float*)d_in[2];
    const float* W0 = (const float*)d_in[3];
    const float* b0 = (const float*)d_in[4];
    const float* W1 = (const float*)d_in[5];
    const float* b1 = (const float*)d_in[6];
    const float* W2 = (const float*)d_in[7];
    const float* b2 = (const float*)d_in[8];
    const int* src = ei;
    const int* dst = ei + N_EDGES;
    float* outp = (float*)d_out;

    // workspace carve-up (8B-aligned first)
    char* ws = (char*)d_ws;
    int2*  csr      = (int2*)ws;   ws += (size_t)N_EDGES * 8;
    float* dis      = (float*)ws;  ws += N_NODES * 4;
    float* selfnorm = (float*)ws;  ws += N_NODES * 4;
    int*   cnt      = (int*)ws;    ws += N_NODES * 4;
    int*   row      = (int*)ws;    ws += N_NODES * 4;
    int*   bsum     = (int*)ws;    ws += 512 * 4;
    int*   boff     = (int*)ws;    ws += 512 * 4;
    f16*   xh       = (f16*)ws;    ws += (size_t)N_NODES * F_IN * 2;
    f16*   Wt0      = (f16*)ws;    ws += F_IN * HID * 2;
    f16*   Wt1      = (f16*)ws;    ws += HID * HID * 2;
    f16*   Wt2      = (f16*)ws;    ws += HID * NCLS * 2;
    f16*   bufA     = (f16*)ws;    ws += (size_t)N_NODES * HID * 2;
    f16*   bufB     = (f16*)ws;    ws += (size_t)N_NODES * HID * 2;

    const int nb = (N_NODES + 255) / 256;
    const int eb = (N_EDGES + 255) / 256;

    // ---- CSR build + norm ----
    k_zero<<<nb, 256, 0, stream>>>(cnt, N_NODES);
    k_cnt<<<eb, 256, 0, stream>>>(dst, cnt, N_EDGES);
    k_scan1<<<nb, 256, 0, stream>>>(cnt, row, bsum, N_NODES);
    k_scan2<<<1, 512, 0, stream>>>(bsum, boff, nb);
    k_scan3<<<nb, 256, 0, stream>>>(row, cnt, boff, N_NODES);
    k_scatter<<<eb, 256, 0, stream>>>(src, dst, ew, row, csr, N_EDGES);
    k_segdeg<<<nb, 256, 0, stream>>>(csr, row, cnt, dis, selfnorm, N_NODES);
    k_renorm<<<(N_NODES * 4 + 255) / 256, 256, 0, stream>>>(csr, row, cnt, dis, N_NODES);

    // ---- fp16 conversions ----
    k_f32_to_f16<<<(N_NODES * (F_IN / 4) + 255) / 256, 256, 0, stream>>>(x, xh, N_NODES * (F_IN / 4));
    k_wt<<<(F_IN * HID + 255) / 256, 256, 0, stream>>>(W0, Wt0, F_IN, HID);
    k_wt<<<(HID * HID + 255) / 256, 256, 0, stream>>>(W1, Wt1, HID, HID);
    k_wt<<<(HID * NCLS + 255) / 256, 256, 0, stream>>>(W2, Wt2, HID, NCLS);

    const int gX = (N_NODES + 255) / 256;

    // ---- layer 1: g1 = A*X (128-wide gather), H1 = relu(g1 @ W0 + b0) ----
    agg_csr<F_IN, 16, false, false><<<(N_NODES + 15) / 16, 256, 0, stream>>>(
        xh, csr, row, cnt, selfnorm, nullptr, bufA, N_NODES);
    gemm_mfma<F_IN, HID, true><<<dim3(gX, HID / 64), 256, 0, stream>>>(bufA, Wt0, b0, bufB, N_NODES);

    // ---- layer 2: g2 = A*H1 (256-wide gather), H2 = relu(g2 @ W1 + b1) ----
    agg_csr<HID, 32, false, false><<<(N_NODES + 7) / 8, 256, 0, stream>>>(
        bufB, csr, row, cnt, selfnorm, nullptr, bufA, N_NODES);
    gemm_mfma<HID, HID, true><<<dim3(gX, HID / 64), 256, 0, stream>>>(bufA, Wt1, b1, bufB, N_NODES);

    // ---- layer 3: P = H2 @ W2 (no act), out = A*P + b2 (64-wide gather) ----
    gemm_mfma<HID, NCLS, false><<<dim3(gX, NCLS / 64), 256, 0, stream>>>(bufB, Wt2, nullptr, bufA, N_NODES);
    agg_csr<NCLS, 8, true, true><<<(N_NODES + 31) / 32, 256, 0, stream>>>(
        bufA, csr, row, cnt, selfnorm, b2, outp, N_NODES);
}

// Round 7
// 553.010 us; speedup vs baseline: 1.1649x; 1.1649x over previous
//
#include <hip/hip_runtime.h>

#define N_NODES 100000
#define F_IN 128
#define HID 256
#define NCLS 64
#define N_EDGES 1600000

typedef _Float16 f16;
typedef f16 half8 __attribute__((ext_vector_type(8)));
typedef f16 half4 __attribute__((ext_vector_type(4)));
typedef float f32x4 __attribute__((ext_vector_type(4)));

#define FIXED_SCALE 67108864.0f   // 2^26

// ---------------------------------------------------------------------------
// degp[i]: packed u64 = (edge_count << 40) | fixed_point_26(weighted_deg)
// Init = fixed-point 1.0 (the self-loop weight), count 0.   <-- R5 bug was 0
// ---------------------------------------------------------------------------
__global__ void k_init(unsigned long long* __restrict__ degp, int n) {
    int i = blockIdx.x * 256 + threadIdx.x;
    if (i < n) degp[i] = (unsigned long long)(1u << 26);
}

// Mega kernel: k_deg atomics (blocks [0,EB)) run with idle VALU/HBM pipes;
// fp16 conversions ride along in trailing blocks, hidden under the atomic
// latency envelope. All parts are mutually independent.
#define EB   6250    // N_EDGES/256
#define XB   12500   // N_NODES*F_IN/4/256
#define W0B  128     // F_IN*HID/256
#define W1B  256     // HID*HID/256
#define W2B  64      // HID*NCLS/256
__global__ __launch_bounds__(256) void mega1(
        const int* __restrict__ dst, const float* __restrict__ ew,
        unsigned long long* __restrict__ degp, int* __restrict__ seq,
        const float* __restrict__ x, f16* __restrict__ xh,
        const float* __restrict__ W0, f16* __restrict__ Wt0,
        const float* __restrict__ W1, f16* __restrict__ Wt1,
        const float* __restrict__ W2, f16* __restrict__ Wt2) {
    int bid = blockIdx.x;
    int t = threadIdx.x;
    if (bid < EB) {
        int i = bid * 256 + t;
        if (i < N_EDGES) {
            unsigned long long c = (1ULL << 40) |
                (unsigned long long)__float2uint_rn(ew[i] * FIXED_SCALE);
            unsigned long long old = atomicAdd(&degp[dst[i]], c);
            seq[i] = (int)(old >> 40);       // this edge's slot within its dst segment
        }
    } else if (bid < EB + XB) {
        int i = (bid - EB) * 256 + t;        // float4 index over x
        if (i < N_NODES * (F_IN / 4)) {
            float4 v = *(const float4*)&x[(size_t)i * 4];
            half4 o;
            o[0] = (f16)v.x; o[1] = (f16)v.y; o[2] = (f16)v.z; o[3] = (f16)v.w;
            *(half4*)&xh[(size_t)i * 4] = o;
        }
    } else if (bid < EB + XB + W0B) {
        int i = (bid - EB - XB) * 256 + t;   // W0[F_IN][HID] -> Wt0[HID][F_IN]
        int k = i / HID, d = i % HID;
        Wt0[d * F_IN + k] = (f16)W0[i];
    } else if (bid < EB + XB + W0B + W1B) {
        int i = (bid - EB - XB - W0B) * 256 + t;
        int k = i / HID, d = i % HID;
        Wt1[d * HID + k] = (f16)W1[i];
    } else {
        int i = (bid - EB - XB - W0B - W1B) * 256 + t;
        int k = i / NCLS, d = i % NCLS;
        Wt2[d * HID + k] = (f16)W2[i];
    }
}

__global__ void k_dis(const unsigned long long* __restrict__ degp,
                      float* __restrict__ dis, float* __restrict__ selfnorm,
                      int* __restrict__ cnt, int n) {
    int i = blockIdx.x * 256 + threadIdx.x;
    if (i < n) {
        unsigned long long p = degp[i];
        cnt[i] = (int)(p >> 40);
        float deg = (float)(p & ((1ULL << 40) - 1)) * (1.0f / FIXED_SCALE);
        float d = rsqrtf(deg);
        dis[i] = d;
        selfnorm[i] = d * d;
    }
}

__global__ void k_scan1(const int* __restrict__ cnt, int* __restrict__ incl,
                        int* __restrict__ bsum, int n) {
    __shared__ int s[256];
    int t = threadIdx.x;
    int i = blockIdx.x * 256 + t;
    int v = (i < n) ? cnt[i] : 0;
    s[t] = v;
    __syncthreads();
    #pragma unroll
    for (int off = 1; off < 256; off <<= 1) {
        int x = (t >= off) ? s[t - off] : 0;
        __syncthreads();
        s[t] += x;
        __syncthreads();
    }
    if (i < n) incl[i] = s[t];
    if (t == 255) bsum[blockIdx.x] = s[255];
}

__global__ void k_scan2(const int* __restrict__ bsum, int* __restrict__ boff, int nb) {
    __shared__ int s[512];
    int t = threadIdx.x;
    int v = (t < nb) ? bsum[t] : 0;
    s[t] = v;
    __syncthreads();
    #pragma unroll
    for (int off = 1; off < 512; off <<= 1) {
        int x = (t >= off) ? s[t - off] : 0;
        __syncthreads();
        s[t] += x;
        __syncthreads();
    }
    if (t < nb) boff[t] = s[t] - v;
}

// row[i] = global exclusive start (in-place over incl); row is NOT mutated later
__global__ void k_scan3(int* __restrict__ row, const int* __restrict__ cnt,
                        const int* __restrict__ boff, int n) {
    int i = blockIdx.x * 256 + threadIdx.x;
    if (i < n) row[i] = row[i] - cnt[i] + boff[i >> 8];
}

// atomic-free placement: pos = row_start[dst] + seq (from mega1's atomic return)
__global__ void k_place(const int* __restrict__ src, const int* __restrict__ dst,
                        const float* __restrict__ w, const int* __restrict__ seq,
                        const int* __restrict__ row, const float* __restrict__ dis,
                        int2* __restrict__ csr, int e) {
    int i = blockIdx.x * 256 + threadIdx.x;
    if (i < e) {
        int s = src[i], d = dst[i];
        float nw = dis[s] * w[i] * dis[d];
        int pos = row[d] + seq[i];
        csr[pos] = make_int2(s, __float_as_int(nw));
    }
}

// ---------------------------------------------------------------------------
// MFMA GEMM: out[n, c] = sum_k in[n, k] * W[k, c]  (+bias, relu if BIAS_RELU)
// Block tile 128x64, 4 waves, each wave 32 rows x 64 cols = 2x4 mfma 16x16x32.
// ---------------------------------------------------------------------------
template <int K, int DOUT, bool BIAS_RELU>
__global__ __launch_bounds__(256) void gemm_mfma(const f16* __restrict__ in,
                                                 const f16* __restrict__ Wt,  // [DOUT][K]
                                                 const float* __restrict__ bias,
                                                 f16* __restrict__ out,
                                                 int nNodes) {
    constexpr int BM = 128, BN = 64, BK = 32;
    constexpr int AP = 40;
    constexpr int CP = 72;
    constexpr int SMEM = (BM * AP + BN * AP) > (BM * CP) ? (BM * AP + BN * AP) : (BM * CP);
    __shared__ f16 smem[SMEM];
    f16* As = smem;
    f16* Bs = smem + BM * AP;

    const int t = threadIdx.x;
    const int w = t >> 6;
    const int lane = t & 63;
    const int quad = lane >> 4;
    const int l16 = lane & 15;
    const int nodeBase = blockIdx.x * BM;
    const int colBase = blockIdx.y * BN;

    f32x4 acc[2][4] = {};

    for (int k0 = 0; k0 < K; k0 += BK) {
        {
            int koff = (t & 3) * 8;
            #pragma unroll
            for (int p = 0; p < 2; ++p) {
                int r = (t >> 2) + p * 64;
                int gn = nodeBase + r;
                if (gn >= nNodes) gn = nNodes - 1;
                half8 v = *(const half8*)&in[(size_t)gn * K + k0 + koff];
                *(half8*)&As[r * AP + koff] = v;
            }
        }
        {
            int koff = (t & 3) * 8;
            int c = t >> 2;
            half8 v = *(const half8*)&Wt[(size_t)(colBase + c) * K + k0 + koff];
            *(half8*)&Bs[c * AP + koff] = v;
        }
        __syncthreads();

        half8 a[2];
        #pragma unroll
        for (int rt = 0; rt < 2; ++rt)
            a[rt] = *(const half8*)&As[(w * 32 + rt * 16 + l16) * AP + quad * 8];
        #pragma unroll
        for (int ct = 0; ct < 4; ++ct) {
            half8 b = *(const half8*)&Bs[(ct * 16 + l16) * AP + quad * 8];
            acc[0][ct] = __builtin_amdgcn_mfma_f32_16x16x32_f16(a[0], b, acc[0][ct], 0, 0, 0);
            acc[1][ct] = __builtin_amdgcn_mfma_f32_16x16x32_f16(a[1], b, acc[1][ct], 0, 0, 0);
        }
        __syncthreads();
    }

    float bv[4];
    #pragma unroll
    for (int ct = 0; ct < 4; ++ct)
        bv[ct] = BIAS_RELU ? bias[colBase + ct * 16 + l16] : 0.0f;

    f16* Cs = smem;
    #pragma unroll
    for (int rt = 0; rt < 2; ++rt)
        #pragma unroll
        for (int ct = 0; ct < 4; ++ct)
            #pragma unroll
            for (int r = 0; r < 4; ++r) {
                int rr = w * 32 + rt * 16 + quad * 4 + r;
                int cc = ct * 16 + l16;
                float v = acc[rt][ct][r];
                if (BIAS_RELU) v = fmaxf(v + bv[ct], 0.0f);
                Cs[rr * CP + cc] = (f16)v;
            }
    __syncthreads();
    #pragma unroll
    for (int p = 0; p < 4; ++p) {
        int r = (t >> 3) + p * 32;
        int gn = nodeBase + r;
        int chunk = (t & 7) * 8;
        if (gn < nNodes)
            *(half8*)&out[(size_t)gn * DOUT + colBase + chunk] =
                *(const half8*)&Cs[r * CP + chunk];
    }
}

// ---------------------------------------------------------------------------
// CSR aggregation (fp16 h): out[d,:] = sn[d]*h[d,:] (+bias) + sum_e w_e*h[src_e,:]
// TPN lanes per node, 8 cols per lane (half8 = 16B), fp32 accumulate.
// row[] holds segment STARTS; end = start + cnt.
// ---------------------------------------------------------------------------
template <int DOUT, int TPN, bool HAS_BIAS, bool OUT_F32>
__global__ __launch_bounds__(256) void agg_csr(const f16* __restrict__ h,
                                               const int2* __restrict__ csr,
                                               const int* __restrict__ row,
                                               const int* __restrict__ cnt,
                                               const float* __restrict__ sn,
                                               const float* __restrict__ bias,
                                               void* __restrict__ outv, int nNodes) {
    constexpr int NPB = 256 / TPN;
    int node = blockIdx.x * NPB + threadIdx.x / TPN;
    if (node >= nNodes) return;
    int lane = threadIdx.x % TPN;
    int col = lane * 8;

    float s = sn[node];
    half8 hv = *(const half8*)&h[(size_t)node * DOUT + col];
    float acc[8];
    #pragma unroll
    for (int i = 0; i < 8; ++i)
        acc[i] = s * (float)hv[i] + (HAS_BIAS ? bias[col + i] : 0.0f);

    int e = row[node];
    int end = e + cnt[node];
    for (; e + 1 < end; e += 2) {
        int2 e0 = csr[e], e1 = csr[e + 1];
        float w0 = __int_as_float(e0.y), w1 = __int_as_float(e1.y);
        half8 a0 = *(const half8*)&h[(size_t)e0.x * DOUT + col];
        half8 a1 = *(const half8*)&h[(size_t)e1.x * DOUT + col];
        #pragma unroll
        for (int i = 0; i < 8; ++i) acc[i] += w0 * (float)a0[i] + w1 * (float)a1[i];
    }
    if (e < end) {
        int2 e0 = csr[e];
        float w0 = __int_as_float(e0.y);
        half8 a0 = *(const half8*)&h[(size_t)e0.x * DOUT + col];
        #pragma unroll
        for (int i = 0; i < 8; ++i) acc[i] += w0 * (float)a0[i];
    }

    if (OUT_F32) {
        float* out = (float*)outv;
        float4 r0 = make_float4(acc[0], acc[1], acc[2], acc[3]);
        float4 r1 = make_float4(acc[4], acc[5], acc[6], acc[7]);
        *(float4*)&out[(size_t)node * DOUT + col] = r0;
        *(float4*)&out[(size_t)node * DOUT + col + 4] = r1;
    } else {
        f16* out = (f16*)outv;
        half8 o;
        #pragma unroll
        for (int i = 0; i < 8; ++i) o[i] = (f16)acc[i];
        *(half8*)&out[(size_t)node * DOUT + col] = o;
    }
}

// ---------------------------------------------------------------------------
extern "C" void kernel_launch(void* const* d_in, const int* in_sizes, int n_in,
                              void* d_out, int out_size, void* d_ws, size_t ws_size,
                              hipStream_t stream) {
    const float* x  = (const float*)d_in[0];
    const int*   ei = (const int*)d_in[1];
    const float* ew = (const float*)d_in[2];
    const float* W0 = (const float*)d_in[3];
    const float* b0 = (const float*)d_in[4];
    const float* W1 = (const float*)d_in[5];
    const float* b1 = (const float*)d_in[6];
    const float* W2 = (const float*)d_in[7];
    const float* b2 = (const float*)d_in[8];
    const int* src = ei;
    const int* dst = ei + N_EDGES;
    float* outp = (float*)d_out;

    // workspace carve-up (8B-aligned first)
    char* ws = (char*)d_ws;
    unsigned long long* degp = (unsigned long long*)ws;  ws += N_NODES * 8;
    int2*  csr      = (int2*)ws;   ws += (size_t)N_EDGES * 8;
    int*   seq      = (int*)ws;    ws += (size_t)N_EDGES * 4;
    float* dis      = (float*)ws;  ws += N_NODES * 4;
    float* selfnorm = (float*)ws;  ws += N_NODES * 4;
    int*   cnt      = (int*)ws;    ws += N_NODES * 4;
    int*   row      = (int*)ws;    ws += N_NODES * 4;
    int*   bsum     = (int*)ws;    ws += 512 * 4;
    int*   boff     = (int*)ws;    ws += 512 * 4;
    f16*   xh       = (f16*)ws;    ws += (size_t)N_NODES * F_IN * 2;
    f16*   Wt0      = (f16*)ws;    ws += F_IN * HID * 2;
    f16*   Wt1      = (f16*)ws;    ws += HID * HID * 2;
    f16*   Wt2      = (f16*)ws;    ws += HID * NCLS * 2;
    f16*   bufA     = (f16*)ws;    ws += (size_t)N_NODES * HID * 2;
    f16*   bufB     = (f16*)ws;    ws += (size_t)N_NODES * HID * 2;

    const int nb = (N_NODES + 255) / 256;   // 391
    const int eb = (N_EDGES + 255) / 256;   // 6250

    // ---- CSR build + norm (conversions hidden under the atomic pass) ----
    k_init<<<nb, 256, 0, stream>>>(degp, N_NODES);
    mega1<<<EB + XB + W0B + W1B + W2B, 256, 0, stream>>>(
        dst, ew, degp, seq, x, xh, W0, Wt0, W1, Wt1, W2, Wt2);
    k_dis<<<nb, 256, 0, stream>>>(degp, dis, selfnorm, cnt, N_NODES);
    k_scan1<<<nb, 256, 0, stream>>>(cnt, row, bsum, N_NODES);
    k_scan2<<<1, 512, 0, stream>>>(bsum, boff, nb);
    k_scan3<<<nb, 256, 0, stream>>>(row, cnt, boff, N_NODES);
    k_place<<<eb, 256, 0, stream>>>(src, dst, ew, seq, row, dis, csr, N_EDGES);

    const int gX = (N_NODES + 127) / 128;

    // ---- layer 1: g1 = A*X (128-wide gather), H1 = relu(g1 @ W0 + b0) ----
    agg_csr<F_IN, 16, false, false><<<(N_NODES + 15) / 16, 256, 0, stream>>>(
        xh, csr, row, cnt, selfnorm, nullptr, bufA, N_NODES);
    gemm_mfma<F_IN, HID, true><<<dim3(gX, HID / 64), 256, 0, stream>>>(bufA, Wt0, b0, bufB, N_NODES);

    // ---- layer 2: g2 = A*H1 (256-wide gather), H2 = relu(g2 @ W1 + b1) ----
    agg_csr<HID, 32, false, false><<<(N_NODES + 7) / 8, 256, 0, stream>>>(
        bufB, csr, row, cnt, selfnorm, nullptr, bufA, N_NODES);
    gemm_mfma<HID, HID, true><<<dim3(gX, HID / 64), 256, 0, stream>>>(bufA, Wt1, b1, bufB, N_NODES);

    // ---- layer 3: P = H2 @ W2 (no act), out = A*P + b2 (64-wide gather) ----
    gemm_mfma<HID, NCLS, false><<<dim3(gX, NCLS / 64), 256, 0, stream>>>(bufB, Wt2, nullptr, bufA, N_NODES);
    agg_csr<NCLS, 8, true, true><<<(N_NODES + 31) / 32, 256, 0, stream>>>(
        bufA, csr, row, cnt, selfnorm, b2, outp, N_NODES);
}